// Round 4
// baseline (252.036 us; speedup 1.0000x reference)
//
#include <hip/hip_runtime.h>
#include <math.h>

#define N 512
#define PLANE ((size_t)N * N)
#define NEG2PI (-6.28318530717958647692f)
#define NBLK_COL 1024              // colfft grid = 128 x 8

// ---------------------------------------------------------------------------
// In-register 8-point complex DFT (DIF), w8 = e^{-2pi i/8}
// ---------------------------------------------------------------------------
__device__ inline void dft8(float (&xr)[8], float (&xi)[8]) {
    const float S = 0.70710678118654752440f;
    float t0r = xr[0] + xr[4], t0i = xi[0] + xi[4];
    float t4r = xr[0] - xr[4], t4i = xi[0] - xi[4];
    float t1r = xr[1] + xr[5], t1i = xi[1] + xi[5];
    float t5r = xr[1] - xr[5], t5i = xi[1] - xi[5];
    float t2r = xr[2] + xr[6], t2i = xi[2] + xi[6];
    float t6r = xr[2] - xr[6], t6i = xi[2] - xi[6];
    float t3r = xr[3] + xr[7], t3i = xi[3] + xi[7];
    float t7r = xr[3] - xr[7], t7i = xi[3] - xi[7];
    float o1r = S * (t5r + t5i), o1i = S * (t5i - t5r);
    float o2r = t6i,             o2i = -t6r;
    float o3r = S * (t7i - t7r), o3i = -S * (t7r + t7i);
    float p0r = t0r + t2r, p0i = t0i + t2i;
    float p1r = t1r + t3r, p1i = t1i + t3i;
    float q0r = t0r - t2r, q0i = t0i - t2i;
    float q1r = t1i - t3i, q1i = -(t1r - t3r);
    xr[0] = p0r + p1r; xi[0] = p0i + p1i;
    xr[4] = p0r - p1r; xi[4] = p0i - p1i;
    xr[2] = q0r + q1r; xi[2] = q0i + q1i;
    xr[6] = q0r - q1r; xi[6] = q0i - q1i;
    float r0r = t4r + o2r, r0i = t4i + o2i;
    float r1r = o1r + o3r, r1i = o1i + o3i;
    float u0r = t4r - o2r, u0i = t4i - o2i;
    float u1r = o1i - o3i, u1i = -(o1r - o3r);
    xr[1] = r0r + r1r; xi[1] = r0i + r1i;
    xr[5] = r0r - r1r; xi[5] = r0i - r1i;
    xr[3] = u0r + u1r; xi[3] = u0i + u1i;
    xr[7] = u0r - u1r; xi[7] = u0i - u1i;
}

__device__ inline void twiddle_apply(float (&xr)[8], float (&xi)[8], float ang1) {
    float ts, tc;
    __sincosf(ang1, &ts, &tc);
    float wr = tc, wi = ts;
    #pragma unroll
    for (int k = 1; k < 8; ++k) {
        float nr = xr[k] * wr - xi[k] * wi;
        float ni = xr[k] * wi + xi[k] * wr;
        xr[k] = nr; xi[k] = ni;
        float w2r = wr * tc - wi * ts;
        float w2i = wr * ts + wi * tc;
        wr = w2r; wi = w2i;
    }
}

// ---------------------------------------------------------------------------
// Per-wave 512-pt FFT, radix-8 DIF. Input xr/xi[q] = x[lane + 64q].
// Output xr/xi[k] = X[64k + 8*(lane&7) + (lane>>3)] (digit-reversed).
// LDS scratch 576 floats/wave, phys(i) = i + i/8. Wave-synchronous.
// ---------------------------------------------------------------------------
__device__ inline void fft512_wave(float (&xr)[8], float (&xi)[8],
                                   float* sre, float* sim, const int l) {
    dft8(xr, xi);
    twiddle_apply(xr, xi, (NEG2PI / 512.0f) * (float)l);
    const int w0 = l + (l >> 3);
    #pragma unroll
    for (int k = 0; k < 8; ++k) { sre[72 * k + w0] = xr[k]; sim[72 * k + w0] = xi[k]; }
    const int i2 = l & 7;
    const int rbase = 72 * (l >> 3) + i2;
    #pragma unroll
    for (int q = 0; q < 8; ++q) { xr[q] = sre[rbase + 9 * q]; xi[q] = sim[rbase + 9 * q]; }
    dft8(xr, xi);
    twiddle_apply(xr, xi, (NEG2PI / 64.0f) * (float)i2);
    #pragma unroll
    for (int k = 0; k < 8; ++k) { sre[rbase + 9 * k] = xr[k]; sim[rbase + 9 * k] = xi[k]; }
    const int r3 = 9 * l;
    #pragma unroll
    for (int q = 0; q < 8; ++q) { xr[q] = sre[r3 + q]; xi[q] = sim[r3 + q]; }
    dft8(xr, xi);
}

// ---------------------------------------------------------------------------
// Kernel 1: fused T-mean (float4) + real-pair pack + row FFT.
// Stores natural layout ws[j][y][fx] (coalesced: per k, lanes cover one 512B
// segment). Block (0,0) additionally zeroes the bin/counter region.
// ---------------------------------------------------------------------------
__global__ __launch_bounds__(256, 4) void kern_rowfft(const float* __restrict__ in,
                                                      float2* __restrict__ ws,
                                                      float* __restrict__ bins,
                                                      unsigned int* __restrict__ done) {
    __shared__ float sRe[4][576];
    __shared__ float sIm[4][576];
    const int wv = threadIdx.x >> 6;
    const int l  = threadIdx.x & 63;
    const int y  = blockIdx.x * 4 + wv;
    const int j  = blockIdx.y;
    if (blockIdx.x == 0 && j == 0) {
        for (int i = threadIdx.x; i < 8 * 256 + 256; i += 256) bins[i] = 0.f;
        if (threadIdx.x == 0)
            __hip_atomic_store(done, 0u, __ATOMIC_RELAXED, __HIP_MEMORY_SCOPE_AGENT);
    }
    const float* baseA = in + ((size_t)j * 8) * PLANE + (size_t)y * N;
    const float* baseB = in + ((size_t)(j + 8) * 8) * PLANE + (size_t)y * N;
    float* re = sRe[wv];
    float* im = sIm[wv];
    #pragma unroll
    for (int c0 = 0; c0 < 2; ++c0) {
        const int c = l + 64 * c0;
        float4 sa = make_float4(0.f, 0.f, 0.f, 0.f);
        float4 sb = make_float4(0.f, 0.f, 0.f, 0.f);
        #pragma unroll
        for (int tt = 0; tt < 8; ++tt) {
            float4 a = *(const float4*)(baseA + tt * PLANE + 4 * c);
            float4 b = *(const float4*)(baseB + tt * PLANE + 4 * c);
            sa.x += a.x; sa.y += a.y; sa.z += a.z; sa.w += a.w;
            sb.x += b.x; sb.y += b.y; sb.z += b.z; sb.w += b.w;
        }
        const int i0 = 4 * c;
        const int p0 = i0 + (i0 >> 3);
        re[p0 + 0] = sa.x * 0.125f; re[p0 + 1] = sa.y * 0.125f;
        re[p0 + 2] = sa.z * 0.125f; re[p0 + 3] = sa.w * 0.125f;
        im[p0 + 0] = sb.x * 0.125f; im[p0 + 1] = sb.y * 0.125f;
        im[p0 + 2] = sb.z * 0.125f; im[p0 + 3] = sb.w * 0.125f;
    }
    float xr[8], xi[8];
    #pragma unroll
    for (int q = 0; q < 8; ++q) {
        const int p = l + (l >> 3) + 72 * q;
        xr[q] = re[p]; xi[q] = im[p];
    }
    fft512_wave(xr, xi, re, im, l);
    float2* wp = ws + ((size_t)j << 18) + ((size_t)y << 9);
    #pragma unroll
    for (int k = 0; k < 8; ++k) {
        wp[64 * k + 8 * (l & 7) + (l >> 3)] = make_float2(xr[k], xi[k]);
    }
}

// ---------------------------------------------------------------------------
// Kernel 2: column FFT + radial binning + fused loss (last-block-done).
// 256 threads / 4 waves, one fx column per wave (register profile identical
// to rowfft -> no spill risk under (256,4)). Slab [512y][4fx] float4 loads,
// pitch-5 LDS transpose (gcd(5,32)=1, conflict-free), FFT scratch aliases
// the slab behind a barrier.
// ---------------------------------------------------------------------------
__global__ __launch_bounds__(256, 4) void kern_colfft(const float2* __restrict__ ws,
                                                      float* __restrict__ gseg,
                                                      float* __restrict__ gcnt,
                                                      unsigned int* __restrict__ done,
                                                      float* __restrict__ out) {
    __shared__ float sA[2560];      // slab re [y*5+f] / 4x576 FFT scratch
    __shared__ float sB[2560];      // slab im
    __shared__ float lseg[256];
    __shared__ float lcnt[256];
    __shared__ int isLast;
    const int t   = threadIdx.x;
    const int w   = t >> 6;
    const int l   = t & 63;
    const int fx0 = blockIdx.x * 4;
    const int j   = blockIdx.y;
    lseg[t] = 0.f;
    lcnt[t] = 0.f;
    const float2* base = ws + ((size_t)j << 18) + fx0;
    // slab load: 512 rows x 4 cols = 2048 float2 = 1024 float4
    #pragma unroll
    for (int i = 0; i < 4; ++i) {
        const int g  = i * 256 + t;
        const int y  = g >> 1;
        const int fp = g & 1;           // float2-pair within the 4 columns
        float4 v = *(const float4*)(base + ((size_t)y << 9) + 2 * fp);
        sA[y * 5 + 2 * fp + 0] = v.x;  sB[y * 5 + 2 * fp + 0] = v.y;
        sA[y * 5 + 2 * fp + 1] = v.z;  sB[y * 5 + 2 * fp + 1] = v.w;
    }
    __syncthreads();                    // slab complete, lseg/lcnt zeroed
    float xr[8], xi[8];
    #pragma unroll
    for (int q = 0; q < 8; ++q) {
        const int y = l + (q << 6);
        xr[q] = sA[y * 5 + w];
        xi[q] = sB[y * 5 + w];
    }
    __syncthreads();                    // extracts done; scratch may alias slab
    fft512_wave(xr, xi, sA + w * 576, sB + w * 576, l);
    const int dx  = fx0 + w - 256;
    const int dx2 = dx * dx;
    #pragma unroll
    for (int k = 0; k < 8; ++k) {
        const int fy = 64 * k + 8 * (l & 7) + (l >> 3);
        const int dy = fy - 256;
        const int d2 = dx2 + dy * dy;
        int r = (int)sqrtf((float)d2);
        if ((r + 1) * (r + 1) <= d2) r++;
        else if (r * r > d2) r--;
        if (r >= 1 && r < 256) {
            atomicAdd(&lseg[r], xr[k] * xr[k] + xi[k] * xi[k]);
            if (j == 0) atomicAdd(&lcnt[r], 1.0f);
        }
    }
    __syncthreads();
    if (lseg[t] != 0.f) atomicAdd(&gseg[j * 256 + t], lseg[t]);
    if (j == 0 && lcnt[t] != 0.f) atomicAdd(&gcnt[t], lcnt[t]);
    __syncthreads();                    // all flush atomics issued & complete
    if (t == 0) {
        __threadfence();
        unsigned int old = __hip_atomic_fetch_add(done, 1u, __ATOMIC_ACQ_REL,
                                                  __HIP_MEMORY_SCOPE_AGENT);
        isLast = (old == NBLK_COL - 1) ? 1 : 0;
    }
    __syncthreads();
    if (!isLast) return;
    // ---- fused loss (only the last-finishing block executes this) ----
    __threadfence();
    float gen = 0.f, refv = 0.f;
    if (t >= 1) {
        float s = 0.f;
        #pragma unroll
        for (int jj = 0; jj < 8; ++jj)
            s += __hip_atomic_load(&gseg[jj * 256 + t], __ATOMIC_RELAXED,
                                   __HIP_MEMORY_SCOPE_AGENT);
        float c = __hip_atomic_load(&gcnt[t], __ATOMIC_RELAXED,
                                    __HIP_MEMORY_SCOPE_AGENT);
        gen  = (c > 0.f) ? s / (fmaxf(c, 1.f) * 16.0f) : 0.f;
        refv = powf((float)t, -5.0f / 3.0f);
    }
    lseg[t] = gen; __syncthreads();
    for (int off = 128; off > 0; off >>= 1) {
        if (t < off) lseg[t] += lseg[t + off];
        __syncthreads();
    }
    const float sgen = lseg[0]; __syncthreads();
    lseg[t] = refv; __syncthreads();
    for (int off = 128; off > 0; off >>= 1) {
        if (t < off) lseg[t] += lseg[t + off];
        __syncthreads();
    }
    const float sref = lseg[0]; __syncthreads();
    const float gn = gen  / (sgen + 1e-8f);
    const float rn = refv / (sref + 1e-8f);
    lseg[t] = (gn - rn) * (gn - rn); __syncthreads();
    for (int off = 128; off > 0; off >>= 1) {
        if (t < off) lseg[t] += lseg[t + off];
        __syncthreads();
    }
    if (t == 0) out[0] = lseg[0] / 255.0f;
}

extern "C" void kernel_launch(void* const* d_in, const int* in_sizes, int n_in,
                              void* d_out, int out_size, void* d_ws, size_t ws_size,
                              hipStream_t stream) {
    const float* in = (const float*)d_in[0];
    float2* planes = (float2*)d_ws;                                  // 16 MiB
    float* bins = (float*)((char*)d_ws + (size_t)8 * N * N * sizeof(float2));
    float* gseg = bins;                          // [8][256]
    float* gcnt = bins + 8 * 256;                // [256]
    unsigned int* done = (unsigned int*)(bins + 8 * 256 + 256);
    kern_rowfft<<<dim3(128, 8), 256, 0, stream>>>(in, planes, bins, done);
    kern_colfft<<<dim3(128, 8), 256, 0, stream>>>(planes, gseg, gcnt, done,
                                                  (float*)d_out);
}

// Round 5
// 247.787 us; speedup vs baseline: 1.0172x; 1.0172x over previous
//
#include <hip/hip_runtime.h>
#include <math.h>

#define N 512
#define PLANE ((size_t)N * N)
#define NEG2PI (-6.28318530717958647692f)

union F2U { float2 f; unsigned long long u; };

// ---------------------------------------------------------------------------
// In-register 8-point complex DFT (DIF), w8 = e^{-2pi i/8}
// ---------------------------------------------------------------------------
__device__ inline void dft8(float (&xr)[8], float (&xi)[8]) {
    const float S = 0.70710678118654752440f;
    float t0r = xr[0] + xr[4], t0i = xi[0] + xi[4];
    float t4r = xr[0] - xr[4], t4i = xi[0] - xi[4];
    float t1r = xr[1] + xr[5], t1i = xi[1] + xi[5];
    float t5r = xr[1] - xr[5], t5i = xi[1] - xi[5];
    float t2r = xr[2] + xr[6], t2i = xi[2] + xi[6];
    float t6r = xr[2] - xr[6], t6i = xi[2] - xi[6];
    float t3r = xr[3] + xr[7], t3i = xi[3] + xi[7];
    float t7r = xr[3] - xr[7], t7i = xi[3] - xi[7];
    float o1r = S * (t5r + t5i), o1i = S * (t5i - t5r);
    float o2r = t6i,             o2i = -t6r;
    float o3r = S * (t7i - t7r), o3i = -S * (t7r + t7i);
    float p0r = t0r + t2r, p0i = t0i + t2i;
    float p1r = t1r + t3r, p1i = t1i + t3i;
    float q0r = t0r - t2r, q0i = t0i - t2i;
    float q1r = t1i - t3i, q1i = -(t1r - t3r);
    xr[0] = p0r + p1r; xi[0] = p0i + p1i;
    xr[4] = p0r - p1r; xi[4] = p0i - p1i;
    xr[2] = q0r + q1r; xi[2] = q0i + q1i;
    xr[6] = q0r - q1r; xi[6] = q0i - q1i;
    float r0r = t4r + o2r, r0i = t4i + o2i;
    float r1r = o1r + o3r, r1i = o1i + o3i;
    float u0r = t4r - o2r, u0i = t4i - o2i;
    float u1r = o1i - o3i, u1i = -(o1r - o3r);
    xr[1] = r0r + r1r; xi[1] = r0i + r1i;
    xr[5] = r0r - r1r; xi[5] = r0i - r1i;
    xr[3] = u0r + u1r; xi[3] = u0i + u1i;
    xr[7] = u0r - u1r; xi[7] = u0i - u1i;
}

__device__ inline void twiddle_apply(float (&xr)[8], float (&xi)[8], float ang1) {
    float ts, tc;
    __sincosf(ang1, &ts, &tc);
    float wr = tc, wi = ts;
    #pragma unroll
    for (int k = 1; k < 8; ++k) {
        float nr = xr[k] * wr - xi[k] * wi;
        float ni = xr[k] * wi + xi[k] * wr;
        xr[k] = nr; xi[k] = ni;
        float w2r = wr * tc - wi * ts;
        float w2i = wr * ts + wi * tc;
        wr = w2r; wi = w2i;
    }
}

// ---------------------------------------------------------------------------
// Per-wave 512-pt FFT, radix-8 DIF. Input xr/xi[q] = x[lane + 64q].
// Output xr/xi[k] = X[64k + 8*(lane&7) + (lane>>3)] (digit-reversed).
// LDS scratch 576 floats/wave, phys(i) = i + i/8. Wave-synchronous (no
// barriers; per-wave scratch only).
// ---------------------------------------------------------------------------
__device__ inline void fft512_wave(float (&xr)[8], float (&xi)[8],
                                   float* sre, float* sim, const int l) {
    dft8(xr, xi);
    twiddle_apply(xr, xi, (NEG2PI / 512.0f) * (float)l);
    const int w0 = l + (l >> 3);
    #pragma unroll
    for (int k = 0; k < 8; ++k) { sre[72 * k + w0] = xr[k]; sim[72 * k + w0] = xi[k]; }
    const int i2 = l & 7;
    const int rbase = 72 * (l >> 3) + i2;
    #pragma unroll
    for (int q = 0; q < 8; ++q) { xr[q] = sre[rbase + 9 * q]; xi[q] = sim[rbase + 9 * q]; }
    dft8(xr, xi);
    twiddle_apply(xr, xi, (NEG2PI / 64.0f) * (float)i2);
    #pragma unroll
    for (int k = 0; k < 8; ++k) { sre[rbase + 9 * k] = xr[k]; sim[rbase + 9 * k] = xi[k]; }
    const int r3 = 9 * l;
    #pragma unroll
    for (int q = 0; q < 8; ++q) { xr[q] = sre[r3 + q]; xi[q] = sim[r3 + q]; }
    dft8(xr, xi);
}

// ---------------------------------------------------------------------------
// Fused kernel: 512 blocks x 512 threads (8 waves), 2 blocks/CU.
//  phase 1: block b -> plane j=b>>6, rows y = (b&63)*8 + wave.
//           T-mean (float4) + real-pair pack + row FFT; coalesced stores to
//           ws[j][y][fx] as agent-scope relaxed atomics (coherent at L3, so
//           no threadfence/L2-writeback is ever needed).
//  per-plane barrier: flags[b]=1 (release); each block waits for the 64
//           producer blocks of its own plane (poison 0xAA != 1, so flags
//           need no initialization; in-order HW dispatch makes the per-plane
//           wait robust even at partial residency).
//  phase 2: 8 columns fx = (b&63)*8 + wave of plane j. Full-line slab load
//           [512y][8fx] (agent atomics), pitch-9 LDS transpose (2-way=free),
//           per-wave col FFT, |Z|^2 radial binning (LDS), one global atomic
//           per bin per block. Plane 0 also accumulates counts.
// ---------------------------------------------------------------------------
__global__ __launch_bounds__(512, 4) void kern_fused(const float* __restrict__ in,
                                                     float2* __restrict__ ws,
                                                     float* __restrict__ gseg,
                                                     float* __restrict__ gcnt,
                                                     unsigned int* __restrict__ flags) {
    __shared__ float sA[4608];      // 8x576 per-wave FFT scratch / slab re [y*9+f]
    __shared__ float sB[4608];      // 8x576 per-wave FFT scratch / slab im
    __shared__ float lseg[256];
    __shared__ float lcnt[256];
    const int t   = threadIdx.x;
    const int w   = t >> 6;
    const int l   = t & 63;
    const int b   = blockIdx.x;
    const int j   = b >> 6;
    const int sub = b & 63;

    // plane-local bin zeroing, ordered before this block's flag release
    if (sub == 0) {
        if (t < 256)
            __hip_atomic_store(&gseg[j * 256 + t], 0.f, __ATOMIC_RELAXED,
                               __HIP_MEMORY_SCOPE_AGENT);
        else if (j == 0)
            __hip_atomic_store(&gcnt[t - 256], 0.f, __ATOMIC_RELAXED,
                               __HIP_MEMORY_SCOPE_AGENT);
    }

    // ---- phase 1: T-mean + pack + row FFT ----
    {
        const int y = sub * 8 + w;
        const float* baseA = in + ((size_t)j * 8) * PLANE + (size_t)y * N;
        const float* baseB = in + ((size_t)(j + 8) * 8) * PLANE + (size_t)y * N;
        float* re = sA + w * 576;
        float* im = sB + w * 576;
        #pragma unroll
        for (int c0 = 0; c0 < 2; ++c0) {
            const int c = l + 64 * c0;
            float4 sa = make_float4(0.f, 0.f, 0.f, 0.f);
            float4 sb = make_float4(0.f, 0.f, 0.f, 0.f);
            #pragma unroll
            for (int tt = 0; tt < 8; ++tt) {
                float4 a  = *(const float4*)(baseA + tt * PLANE + 4 * c);
                float4 bb = *(const float4*)(baseB + tt * PLANE + 4 * c);
                sa.x += a.x;  sa.y += a.y;  sa.z += a.z;  sa.w += a.w;
                sb.x += bb.x; sb.y += bb.y; sb.z += bb.z; sb.w += bb.w;
            }
            const int i0 = 4 * c;
            const int p0 = i0 + (i0 >> 3);       // i0..i0+3 share i>>3
            re[p0 + 0] = sa.x * 0.125f; re[p0 + 1] = sa.y * 0.125f;
            re[p0 + 2] = sa.z * 0.125f; re[p0 + 3] = sa.w * 0.125f;
            im[p0 + 0] = sb.x * 0.125f; im[p0 + 1] = sb.y * 0.125f;
            im[p0 + 2] = sb.z * 0.125f; im[p0 + 3] = sb.w * 0.125f;
        }
        float xr[8], xi[8];
        #pragma unroll
        for (int q = 0; q < 8; ++q) {
            const int p = l + (l >> 3) + 72 * q; // phys(l + 64q)
            xr[q] = re[p]; xi[q] = im[p];
        }
        fft512_wave(xr, xi, re, im, l);
        float2* wp = ws + ((size_t)j << 18) + ((size_t)y << 9);
        #pragma unroll
        for (int k = 0; k < 8; ++k) {
            F2U v; v.f = make_float2(xr[k], xi[k]);
            __hip_atomic_store((unsigned long long*)&wp[64 * k + 8 * (l & 7) + (l >> 3)],
                               v.u, __ATOMIC_RELAXED, __HIP_MEMORY_SCOPE_AGENT);
        }
    }
    __syncthreads();                 // all waves' stores drained (vmcnt(0) at barrier)
    if (t == 0)
        __hip_atomic_store(&flags[b], 1u, __ATOMIC_RELEASE, __HIP_MEMORY_SCOPE_AGENT);

    if (t < 256) { lseg[t] = 0.f; lcnt[t] = 0.f; }
    // ---- per-plane barrier: wait for the 64 producer blocks of plane j ----
    if (t < 64) {
        while (__hip_atomic_load(&flags[j * 64 + t], __ATOMIC_ACQUIRE,
                                 __HIP_MEMORY_SCOPE_AGENT) != 1u)
            __builtin_amdgcn_s_sleep(2);
    }
    __syncthreads();

    // ---- phase 2: slab load + transpose + column FFT + binning ----
    const int fx0 = sub * 8;
    {
        const float2* basep = ws + ((size_t)j << 18) + fx0;
        #pragma unroll
        for (int i = 0; i < 8; ++i) {
            const int y2 = (w << 6) + (i << 3) + (l >> 3);
            const int f  = l & 7;
            F2U v;
            v.u = __hip_atomic_load((const unsigned long long*)&basep[((size_t)y2 << 9) + f],
                                    __ATOMIC_RELAXED, __HIP_MEMORY_SCOPE_AGENT);
            sA[y2 * 9 + f] = v.f.x;
            sB[y2 * 9 + f] = v.f.y;
        }
    }
    __syncthreads();                 // slab complete
    float xr[8], xi[8];
    #pragma unroll
    for (int q = 0; q < 8; ++q) {
        const int y2 = l + (q << 6);
        xr[q] = sA[y2 * 9 + w];
        xi[q] = sB[y2 * 9 + w];
    }
    __syncthreads();                 // extracts done; scratch may alias slab
    fft512_wave(xr, xi, sA + w * 576, sB + w * 576, l);
    const int dx  = fx0 + w - 256;
    const int dx2 = dx * dx;
    #pragma unroll
    for (int k = 0; k < 8; ++k) {
        const int fy = 64 * k + 8 * (l & 7) + (l >> 3);
        const int dy = fy - 256;
        const int d2 = dx2 + dy * dy;
        int r = (int)sqrtf((float)d2);
        if ((r + 1) * (r + 1) <= d2) r++;
        else if (r * r > d2) r--;
        if (r >= 1 && r < 256) {
            atomicAdd(&lseg[r], xr[k] * xr[k] + xi[k] * xi[k]);
            if (j == 0) atomicAdd(&lcnt[r], 1.0f);
        }
    }
    __syncthreads();
    if (t < 256) {
        if (lseg[t] != 0.f) atomicAdd(&gseg[j * 256 + t], lseg[t]);
        if (j == 0 && lcnt[t] != 0.f) atomicAdd(&gcnt[t], lcnt[t]);
    }
}

// ---------------------------------------------------------------------------
// Loss kernel: single block — normalized spectra + MSE (validated R1-R4).
// ---------------------------------------------------------------------------
__global__ __launch_bounds__(256) void kern_loss(const float* __restrict__ gseg,
                                                 const float* __restrict__ gcnt,
                                                 float* __restrict__ out) {
    __shared__ float red[256];
    const int t = threadIdx.x;
    float gen = 0.f, refv = 0.f;
    if (t >= 1) {
        float s = 0.f;
        #pragma unroll
        for (int jj = 0; jj < 8; ++jj) s += gseg[jj * 256 + t];
        float c = gcnt[t];
        gen  = (c > 0.f) ? s / (fmaxf(c, 1.f) * 16.0f) : 0.f;
        refv = powf((float)t, -5.0f / 3.0f);
    }
    red[t] = gen; __syncthreads();
    for (int off = 128; off > 0; off >>= 1) {
        if (t < off) red[t] += red[t + off];
        __syncthreads();
    }
    const float sgen = red[0]; __syncthreads();
    red[t] = refv; __syncthreads();
    for (int off = 128; off > 0; off >>= 1) {
        if (t < off) red[t] += red[t + off];
        __syncthreads();
    }
    const float sref = red[0]; __syncthreads();
    const float gn = gen  / (sgen + 1e-8f);
    const float rn = refv / (sref + 1e-8f);
    red[t] = (gn - rn) * (gn - rn); __syncthreads();
    for (int off = 128; off > 0; off >>= 1) {
        if (t < off) red[t] += red[t + off];
        __syncthreads();
    }
    if (t == 0) out[0] = red[0] / 255.0f;
}

extern "C" void kernel_launch(void* const* d_in, const int* in_sizes, int n_in,
                              void* d_out, int out_size, void* d_ws, size_t ws_size,
                              hipStream_t stream) {
    const float* in = (const float*)d_in[0];
    float2* planes = (float2*)d_ws;                                  // 16 MiB
    float* bins = (float*)((char*)d_ws + (size_t)8 * N * N * sizeof(float2));
    float* gseg = bins;                              // [8][256]
    float* gcnt = bins + 8 * 256;                    // [256]
    unsigned int* flags = (unsigned int*)(bins + 8 * 256 + 256);   // [512]
    kern_fused<<<512, 512, 0, stream>>>(in, planes, gseg, gcnt, flags);
    kern_loss<<<1, 256, 0, stream>>>(gseg, gcnt, (float*)d_out);
}

// Round 6
// 216.582 us; speedup vs baseline: 1.1637x; 1.1441x over previous
//
#include <hip/hip_runtime.h>
#include <math.h>

#define N 512
#define PLANE ((size_t)N * N)
#define NEG2PI (-6.28318530717958647692f)

// ---------------------------------------------------------------------------
// In-register 8-point complex DFT (DIF), w8 = e^{-2pi i/8}  [validated R1-R5]
// ---------------------------------------------------------------------------
__device__ inline void dft8(float (&xr)[8], float (&xi)[8]) {
    const float S = 0.70710678118654752440f;
    float t0r = xr[0] + xr[4], t0i = xi[0] + xi[4];
    float t4r = xr[0] - xr[4], t4i = xi[0] - xi[4];
    float t1r = xr[1] + xr[5], t1i = xi[1] + xi[5];
    float t5r = xr[1] - xr[5], t5i = xi[1] - xi[5];
    float t2r = xr[2] + xr[6], t2i = xi[2] + xi[6];
    float t6r = xr[2] - xr[6], t6i = xi[2] - xi[6];
    float t3r = xr[3] + xr[7], t3i = xi[3] + xi[7];
    float t7r = xr[3] - xr[7], t7i = xi[3] - xi[7];
    float o1r = S * (t5r + t5i), o1i = S * (t5i - t5r);
    float o2r = t6i,             o2i = -t6r;
    float o3r = S * (t7i - t7r), o3i = -S * (t7r + t7i);
    float p0r = t0r + t2r, p0i = t0i + t2i;
    float p1r = t1r + t3r, p1i = t1i + t3i;
    float q0r = t0r - t2r, q0i = t0i - t2i;
    float q1r = t1i - t3i, q1i = -(t1r - t3r);
    xr[0] = p0r + p1r; xi[0] = p0i + p1i;
    xr[4] = p0r - p1r; xi[4] = p0i - p1i;
    xr[2] = q0r + q1r; xi[2] = q0i + q1i;
    xr[6] = q0r - q1r; xi[6] = q0i - q1i;
    float r0r = t4r + o2r, r0i = t4i + o2i;
    float r1r = o1r + o3r, r1i = o1i + o3i;
    float u0r = t4r - o2r, u0i = t4i - o2i;
    float u1r = o1i - o3i, u1i = -(o1r - o3r);
    xr[1] = r0r + r1r; xi[1] = r0i + r1i;
    xr[5] = r0r - r1r; xi[5] = r0i - r1i;
    xr[3] = u0r + u1r; xi[3] = u0i + u1i;
    xr[7] = u0r - u1r; xi[7] = u0i - u1i;
}

__device__ inline void twiddle_apply(float (&xr)[8], float (&xi)[8], float ang1) {
    float ts = __sinf(ang1), tc = __cosf(ang1);
    float wr = tc, wi = ts;
    #pragma unroll
    for (int k = 1; k < 8; ++k) {
        float nr = xr[k] * wr - xi[k] * wi;
        float ni = xr[k] * wi + xi[k] * wr;
        xr[k] = nr; xi[k] = ni;
        float w2r = wr * tc - wi * ts;
        float w2i = wr * ts + wi * tc;
        wr = w2r; wi = w2i;
    }
}

// ---------------------------------------------------------------------------
// Per-wave 512-pt FFT, radix-8 DIF. Input xr/xi[q] = x[lane + 64q].
// Output xr/xi[k] = X[64k + 8*(lane&7) + (lane>>3)] (digit-reversed).
// LDS scratch 576 floats/wave, phys(i) = i + i/8. Wave-synchronous.
// ---------------------------------------------------------------------------
__device__ inline void fft512_wave(float (&xr)[8], float (&xi)[8],
                                   float* sre, float* sim, const int l) {
    dft8(xr, xi);
    twiddle_apply(xr, xi, (NEG2PI / 512.0f) * (float)l);
    const int w0 = l + (l >> 3);
    #pragma unroll
    for (int k = 0; k < 8; ++k) { sre[72 * k + w0] = xr[k]; sim[72 * k + w0] = xi[k]; }
    const int i2 = l & 7;
    const int rbase = 72 * (l >> 3) + i2;
    #pragma unroll
    for (int q = 0; q < 8; ++q) { xr[q] = sre[rbase + 9 * q]; xi[q] = sim[rbase + 9 * q]; }
    dft8(xr, xi);
    twiddle_apply(xr, xi, (NEG2PI / 64.0f) * (float)i2);
    #pragma unroll
    for (int k = 0; k < 8; ++k) { sre[rbase + 9 * k] = xr[k]; sim[rbase + 9 * k] = xi[k]; }
    const int r3 = 9 * l;
    #pragma unroll
    for (int q = 0; q < 8; ++q) { xr[q] = sre[r3 + q]; xi[q] = sim[r3 + q]; }
    dft8(xr, xi);
}

// ---------------------------------------------------------------------------
// Kernel 1: T-mean + real-pair pack + row FFT. Grid 1024 (1-D), 256 thr.
// Plane j = b & 7  ==> all blocks of plane j land on XCD j (b % 8 heuristic),
// so ws[j] stays in that XCD's L2 for kern_colfft (valid-clean after the
// end-of-kernel writeback). Plain stores — inter-kernel flush handles
// coherence. Explicit va/vb arrays force 16 loads in flight (MLP).
// Block 0 also zeroes the bin region (replaces the memset dispatch).
// ---------------------------------------------------------------------------
__global__ __launch_bounds__(256, 4) void kern_rowfft(const float* __restrict__ in,
                                                      float2* __restrict__ ws,
                                                      float* __restrict__ bins) {
    __shared__ float sRe[4][576];
    __shared__ float sIm[4][576];
    const int b   = blockIdx.x;
    const int j   = b & 7;
    const int sub = b >> 3;
    const int wv  = threadIdx.x >> 6;
    const int l   = threadIdx.x & 63;
    const int y   = sub * 4 + wv;
    if (b == 0) {
        #pragma unroll
        for (int i = 0; i < 9; ++i) bins[i * 256 + threadIdx.x] = 0.f;
    }
    const float* baseA = in + ((size_t)j * 8) * PLANE + (size_t)y * N;
    const float* baseB = in + ((size_t)(j + 8) * 8) * PLANE + (size_t)y * N;
    float* re = sRe[wv];
    float* im = sIm[wv];
    #pragma unroll
    for (int c0 = 0; c0 < 2; ++c0) {
        const int c = l + 64 * c0;
        float4 va[8], vb[8];
        #pragma unroll
        for (int tt = 0; tt < 8; ++tt) va[tt] = *(const float4*)(baseA + tt * PLANE + 4 * c);
        #pragma unroll
        for (int tt = 0; tt < 8; ++tt) vb[tt] = *(const float4*)(baseB + tt * PLANE + 4 * c);
        float4 sa, sb;
        sa.x = ((va[0].x + va[1].x) + (va[2].x + va[3].x)) + ((va[4].x + va[5].x) + (va[6].x + va[7].x));
        sa.y = ((va[0].y + va[1].y) + (va[2].y + va[3].y)) + ((va[4].y + va[5].y) + (va[6].y + va[7].y));
        sa.z = ((va[0].z + va[1].z) + (va[2].z + va[3].z)) + ((va[4].z + va[5].z) + (va[6].z + va[7].z));
        sa.w = ((va[0].w + va[1].w) + (va[2].w + va[3].w)) + ((va[4].w + va[5].w) + (va[6].w + va[7].w));
        sb.x = ((vb[0].x + vb[1].x) + (vb[2].x + vb[3].x)) + ((vb[4].x + vb[5].x) + (vb[6].x + vb[7].x));
        sb.y = ((vb[0].y + vb[1].y) + (vb[2].y + vb[3].y)) + ((vb[4].y + vb[5].y) + (vb[6].y + vb[7].y));
        sb.z = ((vb[0].z + vb[1].z) + (vb[2].z + vb[3].z)) + ((vb[4].z + vb[5].z) + (vb[6].z + vb[7].z));
        sb.w = ((vb[0].w + vb[1].w) + (vb[2].w + vb[3].w)) + ((vb[4].w + vb[5].w) + (vb[6].w + vb[7].w));
        const int i0 = 4 * c;
        const int p0 = i0 + (i0 >> 3);       // i0..i0+3 share i>>3
        re[p0 + 0] = sa.x * 0.125f; re[p0 + 1] = sa.y * 0.125f;
        re[p0 + 2] = sa.z * 0.125f; re[p0 + 3] = sa.w * 0.125f;
        im[p0 + 0] = sb.x * 0.125f; im[p0 + 1] = sb.y * 0.125f;
        im[p0 + 2] = sb.z * 0.125f; im[p0 + 3] = sb.w * 0.125f;
    }
    float xr[8], xi[8];
    #pragma unroll
    for (int q = 0; q < 8; ++q) {
        const int p = l + (l >> 3) + 72 * q; // phys(l + 64q)
        xr[q] = re[p]; xi[q] = im[p];
    }
    fft512_wave(xr, xi, re, im, l);
    float2* wp = ws + ((size_t)j << 18) + ((size_t)y << 9);
    #pragma unroll
    for (int k = 0; k < 8; ++k) {
        wp[64 * k + 8 * (l & 7) + (l >> 3)] = make_float2(xr[k], xi[k]);
    }
}

// ---------------------------------------------------------------------------
// Kernel 2: column FFT + radial binning. Grid 512 (1-D), 512 thr / 8 waves.
// Plane j = b & 7 matches rowfft's swizzle -> slab reads hit XCD-local L2.
// Slab [512y][8fx]: one 64B line per 8 lanes, each line read by exactly one
// block. Pitch-9 LDS transpose (2-way = free); FFT scratch aliases the slab
// behind a barrier. [structure validated R3]
// ---------------------------------------------------------------------------
__global__ __launch_bounds__(512, 4) void kern_colfft(const float2* __restrict__ ws,
                                                      float* __restrict__ gseg,
                                                      float* __restrict__ gcnt) {
    __shared__ float sA[8 * 576];
    __shared__ float sB[8 * 576];
    __shared__ float lseg[256];
    __shared__ float lcnt[256];
    const int b   = blockIdx.x;
    const int j   = b & 7;
    const int sub = b >> 3;
    const int fx0 = sub * 8;
    const int t   = threadIdx.x;
    const int w   = t >> 6;
    const int l   = t & 63;
    if (t < 256) { lseg[t] = 0.f; lcnt[t] = 0.f; }
    const float2* base = ws + ((size_t)j << 18) + fx0;
    #pragma unroll
    for (int i = 0; i < 8; ++i) {
        const int y = (w << 6) + (i << 3) + (l >> 3);
        const int f = l & 7;
        float2 v = base[((size_t)y << 9) + f];
        sA[y * 9 + f] = v.x;
        sB[y * 9 + f] = v.y;
    }
    __syncthreads();                 // slab complete, lseg/lcnt zeroed
    float xr[8], xi[8];
    #pragma unroll
    for (int q = 0; q < 8; ++q) {
        const int y = l + (q << 6);
        xr[q] = sA[y * 9 + w];
        xi[q] = sB[y * 9 + w];
    }
    __syncthreads();                 // extracts done; scratch may alias slab
    fft512_wave(xr, xi, sA + w * 576, sB + w * 576, l);
    const int dx  = fx0 + w - 256;
    const int dx2 = dx * dx;
    #pragma unroll
    for (int k = 0; k < 8; ++k) {
        const int fy = 64 * k + 8 * (l & 7) + (l >> 3);
        const int dy = fy - 256;
        const int d2 = dx2 + dy * dy;
        int r = (int)sqrtf((float)d2);
        if ((r + 1) * (r + 1) <= d2) r++;
        else if (r * r > d2) r--;
        if (r >= 1 && r < 256) {
            atomicAdd(&lseg[r], xr[k] * xr[k] + xi[k] * xi[k]);
            if (j == 0) atomicAdd(&lcnt[r], 1.0f);
        }
    }
    __syncthreads();
    if (t < 256) {
        if (lseg[t] != 0.f) atomicAdd(&gseg[j * 256 + t], lseg[t]);
    } else if (j == 0) {
        if (lcnt[t - 256] != 0.f) atomicAdd(&gcnt[t - 256], lcnt[t - 256]);
    }
}

// ---------------------------------------------------------------------------
// Kernel 3: single block — normalized spectra + MSE. [validated R1-R5]
// ---------------------------------------------------------------------------
__global__ __launch_bounds__(256) void kern_loss(const float* __restrict__ gseg,
                                                 const float* __restrict__ gcnt,
                                                 float* __restrict__ out) {
    __shared__ float red[256];
    const int t = threadIdx.x;
    float gen = 0.f, refv = 0.f;
    if (t >= 1) {
        float s = 0.f;
        #pragma unroll
        for (int jj = 0; jj < 8; ++jj) s += gseg[jj * 256 + t];
        float c = gcnt[t];
        gen  = (c > 0.f) ? s / (fmaxf(c, 1.f) * 16.0f) : 0.f;
        refv = exp2f(-1.66666666667f * log2f((float)t));
    }
    red[t] = gen; __syncthreads();
    for (int off = 128; off > 0; off >>= 1) {
        if (t < off) red[t] += red[t + off];
        __syncthreads();
    }
    const float sgen = red[0]; __syncthreads();
    red[t] = refv; __syncthreads();
    for (int off = 128; off > 0; off >>= 1) {
        if (t < off) red[t] += red[t + off];
        __syncthreads();
    }
    const float sref = red[0]; __syncthreads();
    const float gn = gen  / (sgen + 1e-8f);
    const float rn = refv / (sref + 1e-8f);
    red[t] = (gn - rn) * (gn - rn); __syncthreads();
    for (int off = 128; off > 0; off >>= 1) {
        if (t < off) red[t] += red[t + off];
        __syncthreads();
    }
    if (t == 0) out[0] = red[0] / 255.0f;
}

extern "C" void kernel_launch(void* const* d_in, const int* in_sizes, int n_in,
                              void* d_out, int out_size, void* d_ws, size_t ws_size,
                              hipStream_t stream) {
    const float* in = (const float*)d_in[0];
    float2* planes = (float2*)d_ws;                                  // 16 MiB
    float* bins = (float*)((char*)d_ws + (size_t)8 * N * N * sizeof(float2));
    float* gseg = bins;                              // [8][256]
    float* gcnt = bins + 8 * 256;                    // [256]
    kern_rowfft<<<1024, 256, 0, stream>>>(in, planes, bins);
    kern_colfft<<<512, 512, 0, stream>>>(planes, gseg, gcnt);
    kern_loss<<<1, 256, 0, stream>>>(gseg, gcnt, (float*)d_out);
}